// Round 2
// baseline (4582.833 us; speedup 1.0000x reference)
//
#include <hip/hip_runtime.h>
#include <math.h>
#include <stdio.h>

#define BB 4
#define CC 64
#define HH 256
#define WW 256
#define NP 65536
#define NHEADS 8
#define CHD 8
#define HIDF 170
#define HID2 340

__device__ __forceinline__ float gelu_f(float x) {
  return 0.5f * x * (1.f + erff(x * 0.70710678118654752f));
}

// ---------------------------------------------------------------- transpose (B,N,C)->(B,C,N)
__global__ __launch_bounds__(256) void k_transpose(const float* __restrict__ x,
                                                   float* __restrict__ xi) {
  __shared__ float tile[64 * 65];
  int b = blockIdx.y;
  long n0 = (long)blockIdx.x * 64;
  for (int i = threadIdx.x; i < 64 * 64; i += 256) {
    int nl = i >> 6, c = i & 63;
    tile[nl * 65 + c] = x[((long)b * NP + n0 + nl) * 64 + c];
  }
  __syncthreads();
  for (int i = threadIdx.x; i < 64 * 64; i += 256) {
    int c = i >> 6, nl = i & 63;
    xi[((long)b * CC + c) * NP + n0 + nl] = tile[nl * 65 + c];
  }
}

// ---------------------------------------------------------------- per-pixel LN inv-std
__global__ __launch_bounds__(256) void k_sigma(const float* __restrict__ in,
                                               float* __restrict__ sig) {
  long p = (long)blockIdx.x * 256 + threadIdx.x;  // [0, B*NP)
  int b = (int)(p >> 16);
  long n = p & (NP - 1);
  const float* ip = in + (long)b * CC * NP + n;
  float s1 = 0.f, s2 = 0.f;
#pragma unroll
  for (int c = 0; c < 64; c++) {
    float v = ip[(long)c * NP];
    s1 += v; s2 += v * v;
  }
  float mean = s1 * (1.f / 64.f);
  float var = s2 * (1.f / 64.f) - mean * mean;
  sig[p] = rsqrtf(var + 1e-5f);
}

// ---------------------------------------------------------------- mean over space of ln1(x): per (b,c)
__global__ __launch_bounds__(256) void k_mean_sig(const float* __restrict__ xi,
                                                  const float* __restrict__ sig,
                                                  const float* __restrict__ lnw,
                                                  float* __restrict__ mean) {
  int bc = blockIdx.x; int b = bc >> 6, c = bc & 63;
  const float* ip = xi + (long)bc * NP;
  const float* sp = sig + (long)b * NP;
  float s = 0.f;
  for (int i = threadIdx.x; i < NP; i += 256) s += ip[i] * sp[i];
  __shared__ float red[256];
  red[threadIdx.x] = s; __syncthreads();
  for (int st = 128; st > 0; st >>= 1) {
    if (threadIdx.x < st) red[threadIdx.x] += red[threadIdx.x + st];
    __syncthreads();
  }
  if (threadIdx.x == 0) mean[bc] = red[0] * lnw[c] * (1.f / (float)NP);
}

// ---------------------------------------------------------------- xsca = sca_w @ mean + sca_b
__global__ void k_xsca(const float* __restrict__ mean, const float* __restrict__ sca_w,
                       const float* __restrict__ sca_b, float* __restrict__ xsca) {
  int t = threadIdx.x;  // 256 = B*C
  int b = t >> 6, co = t & 63;
  float a = sca_b[co];
  for (int ci = 0; ci < 64; ci++) a += sca_w[co * 64 + ci] * mean[b * 64 + ci];
  xsca[t] = a;
}

// ---------------------------------------------------------------- fold LN weight + transpose: o[ci][co] = w[co][ci]*lnw[ci]
__global__ void k_foldT(const float* __restrict__ w, const float* __restrict__ lnw,
                        float* __restrict__ o, int CO) {
  int i = blockIdx.x * 256 + threadIdx.x;
  if (i < CO * 64) { int co = i >> 6, ci = i & 63; o[ci * CO + co] = w[i] * lnw[ci]; }
}

// ---------------------------------------------------------------- plain transpose (CO,CI)->(CI,CO)  (CO=64)
__global__ void k_wtrans(const float* __restrict__ w, float* __restrict__ wT,
                         int CO, int CI) {
  int i = blockIdx.x * 256 + threadIdx.x;
  if (i < CO * CI) { int co = i / CI, ci = i - co * CI; wT[ci * CO + co] = w[i]; }
}

// ---------------------------------------------------------------- fused 1x1(64->NCH) * sigma -> dw3x3 -> epilogue
// MODE 0: q/k normalize  (NCH=8, one head)
// MODE 1: v + stats (kv, ksum, vsum) via atomics; reads Kn  (NCH=8)
// MODE 2: dw1+dw2+gelu -> G (NCH=8 staged dw1 rows -> 4 outputs)
// MODE 3: FFN pin+dw+gelu-gate -> Hb (NCH=10: 5 pairs)
template <int MODE, int NCH>
__global__ __launch_bounds__(256) void k_fused(
    const float* __restrict__ xi, const float* __restrict__ sigma,
    const float* __restrict__ w1, int W, const float* __restrict__ w1b,
    const float* __restrict__ dwp, const float* __restrict__ dwpb,
    const float* __restrict__ kn, float* __restrict__ outp,
    float* __restrict__ stats) {
  constexpr int NA = (MODE == 3) ? NCH / 2 : NCH;
  const int t = threadIdx.x;
  const int cy = blockIdx.y, b = blockIdx.z;
  const int tx0 = (blockIdx.x & 7) * 32, ty0 = (blockIdx.x >> 3) * 32;
  __shared__ float su[NCH * 1224];
  __shared__ float ssig[1156];
  __shared__ float sred[80];

  const float* w1p = w1 + cy * NA;
  const float* w1bp = (MODE == 3) ? (w1b + cy * NA) : nullptr;
  const float* dwq = dwp + cy * NA * 9;
  const float* dwqb = (MODE == 3) ? (dwpb + cy * NA * 9) : nullptr;

  for (int i = t; i < 1156; i += 256) {
    int hy = i / 34, hx = i - hy * 34;
    int gy = ty0 - 1 + hy, gx = tx0 - 1 + hx;
    ssig[i] = ((unsigned)gy < 256u && (unsigned)gx < 256u)
                  ? sigma[(long)b * NP + gy * 256 + gx] : 0.f;
  }

  float acc[5][NCH];
#pragma unroll
  for (int j = 0; j < 5; ++j)
#pragma unroll
    for (int c = 0; c < NCH; ++c) acc[j][c] = 0.f;

  const bool has5 = (t + 1024) < 1156;

  for (int c8 = 0; c8 < 8; ++c8) {
    __syncthreads();
    for (int i = t; i < 8 * 1156; i += 256) {
      int cc = i / 1156, p = i - cc * 1156;
      int hy = p / 34, hx = p - hy * 34;
      int gy = ty0 - 1 + hy, gx = tx0 - 1 + hx;
      float v = 0.f;
      if ((unsigned)gy < 256u && (unsigned)gx < 256u)
        v = xi[((long)b * 64 + c8 * 8 + cc) * NP + gy * 256 + gx];
      su[i] = v;
    }
    __syncthreads();
#pragma unroll
    for (int cc = 0; cc < 8; ++cc) {
      int ci = c8 * 8 + cc;
      float wv[NCH];
#pragma unroll
      for (int co = 0; co < NCH; ++co)
        wv[co] = (MODE == 3 && co >= NA) ? w1bp[(long)ci * W + (co - NA)]
                                         : w1p[(long)ci * W + co];
      const float* sxr = su + cc * 1156;
#pragma unroll
      for (int j = 0; j < 4; ++j) {
        float xv = sxr[t + 256 * j];
#pragma unroll
        for (int co = 0; co < NCH; ++co) acc[j][co] += wv[co] * xv;
      }
      if (has5) {
        float xv = sxr[t + 1024];
#pragma unroll
        for (int co = 0; co < NCH; ++co) acc[4][co] += wv[co] * xv;
      }
    }
  }
  __syncthreads();
  // write P halo (= acc * sigma) to LDS, padded layout [co][hy*36+hx]
#pragma unroll
  for (int j = 0; j < 5; ++j) {
    int p = t + 256 * j;
    if (j < 4 || has5) {
      float sg = ssig[p];
      int hy = p / 34, hx = p - hy * 34;
#pragma unroll
      for (int co = 0; co < NCH; ++co) su[co * 1224 + hy * 36 + hx] = acc[j][co] * sg;
    }
  }
  __syncthreads();

  // epilogue: thread owns 4 consecutive outputs in a row
  int oy = t >> 3, ox0 = (t & 7) * 4;
  long nbase = (long)(ty0 + oy) * 256 + tx0 + ox0;
  float dv[NCH][4];
#pragma unroll
  for (int co = 0; co < NCH; ++co) {
    const float* dwr = (MODE == 3 && co >= NA) ? (dwqb + (co - NA) * 9) : (dwq + co * 9);
    float s0 = 0, s1 = 0, s2 = 0, s3 = 0;
#pragma unroll
    for (int dy = 0; dy < 3; ++dy) {
      const float* row = su + co * 1224 + (oy + dy) * 36 + ox0;
      float r0 = row[0], r1 = row[1], r2 = row[2], r3 = row[3], r4 = row[4], r5 = row[5];
      float w0 = dwr[dy * 3], w1v = dwr[dy * 3 + 1], w2 = dwr[dy * 3 + 2];
      s0 += w0 * r0 + w1v * r1 + w2 * r2;
      s1 += w0 * r1 + w1v * r2 + w2 * r3;
      s2 += w0 * r2 + w1v * r3 + w2 * r4;
      s3 += w0 * r3 + w1v * r4 + w2 * r5;
    }
    dv[co][0] = s0; dv[co][1] = s1; dv[co][2] = s2; dv[co][3] = s3;
  }

  if (MODE == 0) {
    float ss[4] = {0, 0, 0, 0};
#pragma unroll
    for (int co = 0; co < NCH; ++co)
#pragma unroll
      for (int x = 0; x < 4; ++x) ss[x] += dv[co][x] * dv[co][x];
    float sc[4];
#pragma unroll
    for (int x = 0; x < 4; ++x) sc[x] = 1.f / (sqrtf(ss[x]) + 1e-6f);
#pragma unroll
    for (int co = 0; co < NCH; ++co) {
      float4 o;
      o.x = dv[co][0] * sc[0]; o.y = dv[co][1] * sc[1];
      o.z = dv[co][2] * sc[2]; o.w = dv[co][3] * sc[3];
      *(float4*)(outp + ((long)b * 64 + cy * 8 + co) * NP + nbase) = o;
    }
  } else if (MODE == 1) {
    float kvv[8][4];
#pragma unroll
    for (int co = 0; co < 8; ++co) {
      float4 kk = *(const float4*)(kn + ((long)b * 64 + cy * 8 + co) * NP + nbase);
      kvv[co][0] = kk.x; kvv[co][1] = kk.y; kvv[co][2] = kk.z; kvv[co][3] = kk.w;
    }
    float kv[64], ks[8], vs[8];
#pragma unroll
    for (int i = 0; i < 64; ++i) kv[i] = 0.f;
#pragma unroll
    for (int i = 0; i < 8; ++i) { ks[i] = 0.f; vs[i] = 0.f; }
#pragma unroll
    for (int x = 0; x < 4; ++x) {
#pragma unroll
      for (int i = 0; i < 8; ++i) { ks[i] += kvv[i][x]; vs[i] += dv[i][x]; }
#pragma unroll
      for (int i = 0; i < 8; ++i)
#pragma unroll
        for (int j2 = 0; j2 < 8; ++j2) kv[i * 8 + j2] += kvv[i][x] * dv[j2][x];
    }
    if (t < 80) sred[t] = 0.f;
    __syncthreads();
    int lane = t & 63;
#pragma unroll
    for (int i = 0; i < 64; ++i) {
      float a = kv[i];
      for (int off = 32; off; off >>= 1) a += __shfl_down(a, off);
      if (lane == 0) atomicAdd(&sred[i], a);
    }
#pragma unroll
    for (int i = 0; i < 8; ++i) {
      float a = ks[i];
      for (int off = 32; off; off >>= 1) a += __shfl_down(a, off);
      if (lane == 0) atomicAdd(&sred[64 + i], a);
      float c2 = vs[i];
      for (int off = 32; off; off >>= 1) c2 += __shfl_down(c2, off);
      if (lane == 0) atomicAdd(&sred[72 + i], c2);
    }
    __syncthreads();
    if (t < 80) atomicAdd(&stats[((long)b * 8 + cy) * 80 + t], sred[t]);
  } else if (MODE == 2) {
#pragma unroll
    for (int c = 0; c < 4; ++c) {
      float4 o;
      o.x = gelu_f(dv[2 * c][0] + dv[2 * c + 1][0]);
      o.y = gelu_f(dv[2 * c][1] + dv[2 * c + 1][1]);
      o.z = gelu_f(dv[2 * c][2] + dv[2 * c + 1][2]);
      o.w = gelu_f(dv[2 * c][3] + dv[2 * c + 1][3]);
      *(float4*)(outp + ((long)b * 64 + cy * 4 + c) * NP + nbase) = o;
    }
  } else {
#pragma unroll
    for (int i = 0; i < 5; ++i) {
      float4 o;
      o.x = gelu_f(dv[i][0]) * dv[5 + i][0];
      o.y = gelu_f(dv[i][1]) * dv[5 + i][1];
      o.z = gelu_f(dv[i][2]) * dv[5 + i][2];
      o.w = gelu_f(dv[i][3]) * dv[5 + i][3];
      *(float4*)(outp + ((long)b * 170 + cy * 5 + i) * NP + nbase) = o;
    }
  }
}

// ---------------------------------------------------------------- per-head refine conv (3/5/7) + sigmoid
__global__ __launch_bounds__(256) void k_refine(
    const float* __restrict__ Qn, const float* __restrict__ Kn,
    const float* __restrict__ r3w, const float* __restrict__ r3b,
    const float* __restrict__ r5w, const float* __restrict__ r5b,
    const float* __restrict__ r7w, const float* __restrict__ r7b,
    float* __restrict__ refw) {
  int bh = blockIdx.z; int b = bh >> 3, h = bh & 7;
  int win; const float* wp; float bias;
  if (h < 2)      { win = 3; wp = r3w + h * 16 * 9;        bias = r3b[h]; }
  else if (h < 5) { win = 5; wp = r5w + (h - 2) * 16 * 25; bias = r5b[h - 2]; }
  else            { win = 7; wp = r7w + (h - 5) * 16 * 49; bias = r7b[h - 5]; }
  int R = win >> 1;
  int T = 16 + 2 * R;
  __shared__ float tile[16 * 22 * 22];
  int x0 = blockIdx.x * 16, y0 = blockIdx.y * 16;
  int tot = 16 * T * T;
  for (int e = threadIdx.x; e < tot; e += 256) {
    int ch = e / (T * T); int r = e - ch * (T * T);
    int yy = r / T, xx = r - yy * T;
    int gy = y0 - R + yy, gx = x0 - R + xx;
    float val = 0.f;
    if (gy >= 0 && gy < HH && gx >= 0 && gx < WW) {
      const float* base = (ch < 8) ? (Qn + ((long)b * 64 + h * 8 + ch) * NP)
                                   : (Kn + ((long)b * 64 + h * 8 + ch - 8) * NP);
      val = base[gy * WW + gx];
    }
    tile[ch * (T * T) + r] = val;
  }
  __syncthreads();
  int tx = threadIdx.x & 15, ty = threadIdx.x >> 4;
  float a = bias;
  for (int ch = 0; ch < 16; ch++) {
    const float* tp = tile + ch * T * T;
    const float* wc = wp + ch * win * win;
    for (int dy = 0; dy < win; dy++)
      for (int dx = 0; dx < win; dx++)
        a += wc[dy * win + dx] * tp[(ty + dy) * T + (tx + dx)];
  }
  a = 1.f / (1.f + expf(-a));
  refw[(long)bh * NP + (y0 + ty) * WW + x0 + tx] = a;
}

// ---------------------------------------------------------------- linear-attention epilogue
__global__ __launch_bounds__(256) void k_attn_out(
    const float* __restrict__ Qn, const float* __restrict__ stats,
    const float* __restrict__ refw, const float* __restrict__ temperature,
    const float* __restrict__ xsca, const float* __restrict__ gx1,
    float* __restrict__ outO) {
  int bh = blockIdx.y; int b = bh >> 3, h = bh & 7;
  __shared__ float s[80];
  if (threadIdx.x < 80) s[threadIdx.x] = stats[bh * 80 + threadIdx.x];
  __syncthreads();
  long n = (long)blockIdx.x * 256 + threadIdx.x;
  const float* qp = Qn + ((long)b * 64 + h * 8) * NP + n;
  float q[8];
#pragma unroll
  for (int i = 0; i < 8; i++) q[i] = qp[(long)i * NP];
  float den = (float)NP + 1e-6f;
#pragma unroll
  for (int i = 0; i < 8; i++) den += q[i] * s[64 + i];
  float rden = 1.f / den;
  float tmp = temperature[h] * refw[(long)bh * NP + n];
  const float* gp = gx1 + ((long)b * 64 + h * 8) * NP + n;
  float* op = outO + ((long)b * 64 + h * 8) * NP + n;
#pragma unroll
  for (int j = 0; j < 8; j++) {
    float num = s[72 + j];
#pragma unroll
    for (int i = 0; i < 8; i++) num += q[i] * s[i * 8 + j];
    float o = num * rden * tmp;
    o *= xsca[b * 64 + h * 8 + j] * gp[(long)j * NP];
    op[(long)j * NP] = o;
  }
}

// ---------------------------------------------------------------- 1x1 GEMM (CO=64), wT global [ci][64], uniform s_loads
__global__ __launch_bounds__(256) void k_gemm(
    const float* __restrict__ in, long in_bs, const float* __restrict__ wT, int CI,
    float* __restrict__ out, const float* __restrict__ addend) {
  int n = blockIdx.x * 256 + threadIdx.x;
  int b = blockIdx.z;
  const float* ip = in + (long)b * in_bs + n;
  float acc[64];
#pragma unroll
  for (int j = 0; j < 64; j++) acc[j] = 0.f;
#pragma unroll 4
  for (int ci = 0; ci < CI; ci++) {
    float x = ip[(long)ci * NP];
    const float* wr = wT + (long)ci * 64;
#pragma unroll
    for (int j = 0; j < 64; j++) acc[j] += wr[j] * x;
  }
  float* op = out + (long)b * 64 * NP + n;
  const float* ap = addend + (long)b * 64 * NP + n;
#pragma unroll
  for (int j = 0; j < 64; j++) op[(long)j * NP] = acc[j] + ap[(long)j * NP];
}

// ================================================================ launcher
extern "C" void kernel_launch(void* const* d_in, const int* in_sizes, int n_in,
                              void* d_out, int out_size, void* d_ws, size_t ws_size,
                              hipStream_t stream) {
  const float* x        = (const float*)d_in[0];
  const float* ln1_w    = (const float*)d_in[1];
  const float* sca_w    = (const float*)d_in[2];
  const float* sca_b    = (const float*)d_in[3];
  const float* dw1_w    = (const float*)d_in[4];
  const float* dw2_w    = (const float*)d_in[5];
  const float* qkv_w    = (const float*)d_in[6];
  const float* qkv_dw_w = (const float*)d_in[7];
  const float* temp     = (const float*)d_in[8];
  const float* r3w = (const float*)d_in[9],  *r3b = (const float*)d_in[10];
  const float* r5w = (const float*)d_in[11], *r5b = (const float*)d_in[12];
  const float* r7w = (const float*)d_in[13], *r7b = (const float*)d_in[14];
  const float* proj_w   = (const float*)d_in[15];
  const float* ln2_w    = (const float*)d_in[16];
  const float* pin_w    = (const float*)d_in[17];
  const float* ffn_dw_w = (const float*)d_in[18];
  const float* pout_w   = (const float*)d_in[19];
  float* out = (float*)d_out;
  float* ws  = (float*)d_ws;

  const long U = 16777216;  // B*64*NP
  float* Qn = ws;           // 1U
  float* Kn = ws + U;       // 1U (later O)
  float* G  = ws + 2 * U;   // 1U
  float* B3 = ws + 3 * U;   // small region
  float* sigma1 = B3;
  float* sigma2 = B3 + 262144;
  float* stats  = B3 + 524288;   // 2560
  float* meanb  = B3 + 526848;   // 256
  float* xscab  = B3 + 527104;   // 256
  float* refW   = B3 + 527360;   // 2097152
  float* wfqT   = B3 + 2624512;  // 64*192
  float* wfd1T  = B3 + 2636800;  // 64*128
  float* wfpinT = B3 + 2644992;  // 64*340
  float* wTproj = B3 + 2666752;  // 64*64
  float* wTpout = B3 + 2670848;  // 170*64 -> ends 2681728
  float* O  = Kn;
  float* Hb = ws;                // 170ch = 44564480 floats, reuses Qn/O/G after death

  const size_t needed = (size_t)(3 * U + 2681728) * 4;
  if (ws_size < needed) {
    fprintf(stderr, "kernel_launch: ws_size %zu < needed %zu\n", ws_size, needed);
    return;
  }

  // xi (NCHW) lives in d_out; residuals accumulate there
  k_transpose<<<dim3(1024, BB), 256, 0, stream>>>(x, out);
  k_sigma<<<1024, 256, 0, stream>>>(out, sigma1);
  k_mean_sig<<<256, 256, 0, stream>>>(out, sigma1, ln1_w, meanb);
  k_xsca<<<1, 256, 0, stream>>>(meanb, sca_w, sca_b, xscab);

  k_foldT<<<48, 256, 0, stream>>>(qkv_w, ln1_w, wfqT, 192);
  k_foldT<<<32, 256, 0, stream>>>(dw1_w, ln1_w, wfd1T, 128);
  k_foldT<<<85, 256, 0, stream>>>(pin_w, ln2_w, wfpinT, 340);
  k_wtrans<<<16, 256, 0, stream>>>(proj_w, wTproj, 64, 64);
  k_wtrans<<<43, 256, 0, stream>>>(pout_w, wTpout, 64, 170);

  // G = gelu(dw2(dw1(ln1(x))))
  k_fused<2, 8><<<dim3(64, 16, BB), 256, 0, stream>>>(
      out, sigma1, wfd1T, 128, nullptr, dw2_w, nullptr, nullptr, G, nullptr);
  // Qn, Kn
  k_fused<0, 8><<<dim3(64, 8, BB), 256, 0, stream>>>(
      out, sigma1, wfqT + 0, 192, nullptr, qkv_dw_w + 0, nullptr, nullptr, Qn, nullptr);
  k_fused<0, 8><<<dim3(64, 8, BB), 256, 0, stream>>>(
      out, sigma1, wfqT + 64, 192, nullptr, qkv_dw_w + 64 * 9, nullptr, nullptr, Kn, nullptr);
  // v + stats
  hipMemsetAsync(stats, 0, 2560 * 4, stream);
  k_fused<1, 8><<<dim3(64, 8, BB), 256, 0, stream>>>(
      out, sigma1, wfqT + 128, 192, nullptr, qkv_dw_w + 128 * 9, nullptr, Kn, nullptr, stats);

  k_refine<<<dim3(16, 16, 32), 256, 0, stream>>>(Qn, Kn, r3w, r3b, r5w, r5b, r7w, r7b, refW);
  k_attn_out<<<dim3(256, 32), 256, 0, stream>>>(Qn, stats, refW, temp, xscab, G, O);

  // proj + residual into d_out
  k_gemm<<<dim3(256, 1, BB), 256, 0, stream>>>(O, 64L * NP, wTproj, 64, out, out);

  // FFN
  k_sigma<<<1024, 256, 0, stream>>>(out, sigma2);
  k_fused<3, 10><<<dim3(64, 34, BB), 256, 0, stream>>>(
      out, sigma2, wfpinT, 340, wfpinT + 170, ffn_dw_w, ffn_dw_w + 170 * 9, nullptr, Hb, nullptr);
  k_gemm<<<dim3(256, 1, BB), 256, 0, stream>>>(Hb, (long)HIDF * NP, wTpout, 170, out, out);
}

// Round 3
// 2004.860 us; speedup vs baseline: 2.2859x; 2.2859x over previous
//
#include <hip/hip_runtime.h>
#include <math.h>
#include <stdio.h>

#define BB 4
#define NP 65536
#define HIDF 170

typedef unsigned short u16;
typedef unsigned int u32;

__device__ __forceinline__ float bf2f(u16 u) { return __uint_as_float((u32)u << 16); }
__device__ __forceinline__ u16 f2bf(float f) {
  u32 u = __float_as_uint(f);
  u = (u + 0x7FFFu + ((u >> 16) & 1u)) >> 16;
  return (u16)u;
}
__device__ __forceinline__ float gelu_f(float x) {
  return 0.5f * x * (1.f + erff(x * 0.70710678118654752f));
}

// ---------------- transpose (B,N,C)->(B,C,N) + sigma1 fold (xb1=xi*sig bf16) + SCA mean partials
__global__ __launch_bounds__(256) void k_trans_stats(const float* __restrict__ x,
                                                     float* __restrict__ xi,
                                                     u16* __restrict__ xb1,
                                                     float* __restrict__ meanraw) {
  __shared__ float tile[64 * 65];
  __shared__ float s1a[64], s2a[64], sig[64], cm[64];
  int b = blockIdx.y;
  long n0 = (long)blockIdx.x * 64;
  int t = threadIdx.x;
  for (int i = t; i < 4096; i += 256) {
    int nl = i >> 6, c = i & 63;
    tile[nl * 65 + c] = x[((long)b * NP + n0 + nl) * 64 + c];
  }
  if (t < 64) { s1a[t] = 0.f; s2a[t] = 0.f; cm[t] = 0.f; }
  __syncthreads();
  {
    int nl = t & 63, part = t >> 6;
    float p1 = 0.f, p2 = 0.f;
    for (int cc = 0; cc < 16; cc++) {
      float v = tile[nl * 65 + part * 16 + cc];
      p1 += v; p2 += v * v;
    }
    atomicAdd(&s1a[nl], p1); atomicAdd(&s2a[nl], p2);
  }
  __syncthreads();
  if (t < 64) {
    float m = s1a[t] * (1.f / 64.f);
    float var = s2a[t] * (1.f / 64.f) - m * m;
    sig[t] = rsqrtf(var + 1e-5f);
  }
  __syncthreads();
  int nl = t & 63;
  float sgv = sig[nl];
  for (int j = 0; j < 16; j++) {
    int i = t + 256 * j;
    int c = i >> 6;                       // wave-uniform
    float v = tile[nl * 65 + c];
    xi[((long)b * 64 + c) * NP + n0 + nl] = v;
    float xbv = v * sgv;
    xb1[((long)b * 64 + c) * NP + n0 + nl] = f2bf(xbv);
    float a = xbv;
    for (int off = 32; off; off >>= 1) a += __shfl_down(a, off);
    if ((t & 63) == 0) atomicAdd(&cm[c], a);
  }
  __syncthreads();
  if (t < 64) atomicAdd(&meanraw[b * 64 + t], cm[t]);
}

// ---------------- xsca
__global__ void k_xsca(const float* __restrict__ meanraw, const float* __restrict__ lnw,
                       const float* __restrict__ sca_w, const float* __restrict__ sca_b,
                       float* __restrict__ xsca) {
  int t = threadIdx.x;  // 256 = B*C
  int b = t >> 6, co = t & 63;
  float a = sca_b[co];
  for (int ci = 0; ci < 64; ci++)
    a += sca_w[co * 64 + ci] * meanraw[b * 64 + ci] * lnw[ci] * (1.f / 65536.f);
  xsca[t] = a;
}

// ---------------- weight prep
__global__ void k_foldW1(const float* __restrict__ qkv_w, const float* __restrict__ dw1_w,
                         const float* __restrict__ lnw, float* __restrict__ W1T) {
  int i = blockIdx.x * 256 + threadIdx.x;
  if (i < 64 * 320) {
    int ci = i / 320, co = i - ci * 320;
    float w = (co < 192) ? qkv_w[co * 64 + ci] : dw1_w[(co - 192) * 64 + ci];
    W1T[i] = w * lnw[ci];
  }
}
__global__ void k_foldW2(const float* __restrict__ pin_w, const float* __restrict__ lnw,
                         float* __restrict__ W2T) {
  int i = blockIdx.x * 256 + threadIdx.x;
  if (i < 64 * 384) {
    int ci = i / 384, co = i - ci * 384;
    W2T[i] = (co < 340) ? pin_w[co * 64 + ci] * lnw[ci] : 0.f;
  }
}
__global__ void k_tproj(const float* __restrict__ w, float* __restrict__ WpT) {
  int i = blockIdx.x * 256 + threadIdx.x;
  if (i < 4096) { int ci = i >> 6, co = i & 63; WpT[ci * 64 + co] = w[co * 64 + ci]; }
}
__global__ void k_tpout(const float* __restrict__ w, float* __restrict__ WoT) {
  int i = blockIdx.x * 256 + threadIdx.x;
  if (i < 170 * 64) { int ci = i >> 6, co = i & 63; WoT[ci * 64 + co] = w[co * 170 + ci]; }
}

// ---------------- 1x1 GEMM 64->64chunk, bf16 in/out, s_load weights
__global__ __launch_bounds__(256) void k_gemm64(const u16* __restrict__ xb,
                                                const float* __restrict__ wT,
                                                int COtot, u16* __restrict__ P) {
  int n = blockIdx.x * 256 + threadIdx.x;
  int co0 = blockIdx.y * 64;
  float acc[64];
#pragma unroll
  for (int j = 0; j < 64; j++) acc[j] = 0.f;
  const u16* ip = xb + n;
  const float* wp = wT + co0;
#pragma unroll 2
  for (int ci = 0; ci < 64; ci++) {
    float xv = bf2f(ip[(long)ci * NP]);
    const float* wr = wp + (long)ci * COtot;
#pragma unroll
    for (int j = 0; j < 64; j++) acc[j] += wr[j] * xv;
  }
  u16* op = P + (long)co0 * NP + n;
#pragma unroll
  for (int j = 0; j < 64; j++) op[(long)j * NP] = f2bf(acc[j]);
}

// ---------------- depthwise 3x3 helper (bf16 global in, bounds-checked)
__device__ __forceinline__ float dwc3(const u16* __restrict__ p, int y, int x,
                                      const float* __restrict__ w9) {
  float a = 0.f;
#pragma unroll
  for (int dy = -1; dy <= 1; dy++) {
    int yy = y + dy; if ((unsigned)yy >= 256u) continue;
#pragma unroll
    for (int dx = -1; dx <= 1; dx++) {
      int xx = x + dx; if ((unsigned)xx >= 256u) continue;
      a += w9[(dy + 1) * 3 + dx + 1] * bf2f(p[yy * 256 + xx]);
    }
  }
  return a;
}

// ---------------- dw3x3 + per-head L2 normalize (q or k)
__global__ __launch_bounds__(256) void k_dwn(const u16* __restrict__ P,
                                             const float* __restrict__ dww,
                                             u16* __restrict__ outp) {
  int n = blockIdx.x * 256 + threadIdx.x;
  int h = blockIdx.y;
  int y = n >> 8, x = n & 255;
  float d[8], ss = 0.f;
#pragma unroll
  for (int c = 0; c < 8; c++) {
    d[c] = dwc3(P + (long)(h * 8 + c) * NP, y, x, dww + (h * 8 + c) * 9);
    ss += d[c] * d[c];
  }
  float sc = 1.f / (sqrtf(ss) + 1e-6f);
#pragma unroll
  for (int c = 0; c < 8; c++) outp[(long)(h * 8 + c) * NP + n] = f2bf(d[c] * sc);
}

// ---------------- dw3x3 v + stats (kv 8x8, ksum, vsum)
__global__ __launch_bounds__(256) void k_dwv(const u16* __restrict__ P,
                                             const float* __restrict__ dww,
                                             const u16* __restrict__ Kn,
                                             float* __restrict__ statsb) {
  int n = blockIdx.x * 256 + threadIdx.x;
  int h = blockIdx.y;
  int y = n >> 8, x = n & 255;
  int t = threadIdx.x;
  float v[8], kk[8];
#pragma unroll
  for (int c = 0; c < 8; c++)
    v[c] = dwc3(P + (long)(h * 8 + c) * NP, y, x, dww + (h * 8 + c) * 9);
#pragma unroll
  for (int c = 0; c < 8; c++) kk[c] = bf2f(Kn[(long)(h * 8 + c) * NP + n]);
  __shared__ float sred[80];
  if (t < 80) sred[t] = 0.f;
  __syncthreads();
#pragma unroll
  for (int i = 0; i < 8; i++)
#pragma unroll
    for (int j = 0; j < 8; j++) {
      float a = kk[i] * v[j];
      for (int off = 32; off; off >>= 1) a += __shfl_down(a, off);
      if ((t & 63) == 0) atomicAdd(&sred[i * 8 + j], a);
    }
#pragma unroll
  for (int i = 0; i < 8; i++) {
    float a = kk[i];
    for (int off = 32; off; off >>= 1) a += __shfl_down(a, off);
    if ((t & 63) == 0) atomicAdd(&sred[64 + i], a);
    float c2 = v[i];
    for (int off = 32; off; off >>= 1) c2 += __shfl_down(c2, off);
    if ((t & 63) == 0) atomicAdd(&sred[72 + i], c2);
  }
  __syncthreads();
  if (t < 80) atomicAdd(&statsb[h * 80 + t], sred[t]);
}

// ---------------- dw1-pairs -> grouped dw2 3x3 -> gelu
__global__ __launch_bounds__(256) void k_dwg(const u16* __restrict__ P,
                                             const float* __restrict__ dw2_w,
                                             u16* __restrict__ G) {
  int n = blockIdx.x * 256 + threadIdx.x;
  int c = blockIdx.y;
  int y = n >> 8, x = n & 255;
  float d1 = dwc3(P + (long)(2 * c) * NP, y, x, dw2_w + (2 * c) * 9);
  float d2 = dwc3(P + (long)(2 * c + 1) * NP, y, x, dw2_w + (2 * c + 1) * 9);
  G[(long)c * NP + n] = f2bf(gelu_f(d1 + d2));
}

// ---------------- FFN dw pair + gelu gate
__global__ __launch_bounds__(256) void k_dwgate(const u16* __restrict__ P,
                                                const float* __restrict__ dww,
                                                u16* __restrict__ Hb) {
  int n = blockIdx.x * 256 + threadIdx.x;
  int c = blockIdx.y;
  int y = n >> 8, x = n & 255;
  float d1 = dwc3(P + (long)c * NP, y, x, dww + c * 9);
  float d2 = dwc3(P + (long)(170 + c) * NP, y, x, dww + (170 + c) * 9);
  Hb[(long)c * NP + n] = f2bf(gelu_f(d1) * d2);
}

// ---------------- refine conv (3/5/7) + sigmoid, 32x32 tile, 4 px/thread
template <int WIN>
__device__ void refine_body(u16* tile, const u16* __restrict__ Qh, const u16* __restrict__ Kh,
                            const float* __restrict__ wp, float bias,
                            float* __restrict__ ro, int x0, int y0) {
  const int R = WIN / 2, T = 32 + 2 * R, TT = T * T;
  int t = threadIdx.x;
  for (int e = t; e < 16 * TT; e += 256) {
    int ch = e / TT, r = e - ch * TT;
    int yy = r / T, xx = r - yy * T;
    int gy = y0 - R + yy, gx = x0 - R + xx;
    u16 val = 0;
    if ((unsigned)gy < 256u && (unsigned)gx < 256u)
      val = (ch < 8) ? Qh[(long)ch * NP + gy * 256 + gx]
                     : Kh[(long)(ch - 8) * NP + gy * 256 + gx];
    tile[ch * TT + r] = val;
  }
  __syncthreads();
  int oy = t >> 3, ox0 = (t & 7) * 4;
  float a0 = bias, a1 = bias, a2 = bias, a3 = bias;
  for (int ch = 0; ch < 16; ch++) {
    const u16* tp = tile + ch * TT;
    const float* wc = wp + ch * WIN * WIN;
#pragma unroll
    for (int dy = 0; dy < WIN; dy++) {
      const u16* row = tp + (oy + dy) * T + ox0;
      float f[WIN + 3];
#pragma unroll
      for (int k2 = 0; k2 < WIN + 3; k2++) f[k2] = bf2f(row[k2]);
#pragma unroll
      for (int dx = 0; dx < WIN; dx++) {
        float w = wc[dy * WIN + dx];
        a0 += w * f[dx]; a1 += w * f[dx + 1]; a2 += w * f[dx + 2]; a3 += w * f[dx + 3];
      }
    }
  }
  float4 o;
  o.x = 1.f / (1.f + expf(-a0)); o.y = 1.f / (1.f + expf(-a1));
  o.z = 1.f / (1.f + expf(-a2)); o.w = 1.f / (1.f + expf(-a3));
  *(float4*)(ro + (long)(y0 + oy) * 256 + x0 + ox0) = o;
}

__global__ __launch_bounds__(256) void k_refine(
    const u16* __restrict__ Qn, const u16* __restrict__ Kn,
    const float* __restrict__ r3w, const float* __restrict__ r3b,
    const float* __restrict__ r5w, const float* __restrict__ r5b,
    const float* __restrict__ r7w, const float* __restrict__ r7b,
    float* __restrict__ refW) {
  __shared__ u16 tile[16 * 38 * 38];
  int bh = blockIdx.z, b = bh >> 3, h = bh & 7;
  const u16* Qh = Qn + ((long)b * 64 + h * 8) * NP;
  const u16* Kh = Kn + ((long)b * 64 + h * 8) * NP;
  float* ro = refW + (long)bh * NP;
  int x0 = blockIdx.x * 32, y0 = blockIdx.y * 32;
  if (h < 2)      refine_body<3>(tile, Qh, Kh, r3w + h * 16 * 9, r3b[h], ro, x0, y0);
  else if (h < 5) refine_body<5>(tile, Qh, Kh, r5w + (h - 2) * 16 * 25, r5b[h - 2], ro, x0, y0);
  else            refine_body<7>(tile, Qh, Kh, r7w + (h - 5) * 16 * 49, r7b[h - 5], ro, x0, y0);
}

// ---------------- linear-attention epilogue
__global__ __launch_bounds__(256) void k_attn_out(
    const u16* __restrict__ Qn, const float* __restrict__ stats,
    const float* __restrict__ refw, const float* __restrict__ temp,
    const float* __restrict__ xsca, const u16* __restrict__ G,
    u16* __restrict__ O) {
  int bh = blockIdx.y, b = bh >> 3, h = bh & 7;
  __shared__ float s[80];
  if (threadIdx.x < 80) s[threadIdx.x] = stats[bh * 80 + threadIdx.x];
  __syncthreads();
  long n = (long)blockIdx.x * 256 + threadIdx.x;
  const u16* qp = Qn + ((long)b * 64 + h * 8) * NP + n;
  float q[8];
#pragma unroll
  for (int i = 0; i < 8; i++) q[i] = bf2f(qp[(long)i * NP]);
  float den = 65536.f + 1e-6f;
#pragma unroll
  for (int i = 0; i < 8; i++) den += q[i] * s[64 + i];
  float rden = 1.f / den;
  float tmp = temp[h] * refw[(long)bh * NP + n];
  const u16* gp = G + ((long)b * 64 + h * 8) * NP + n;
  u16* op = O + ((long)b * 64 + h * 8) * NP + n;
#pragma unroll
  for (int j = 0; j < 8; j++) {
    float num = s[72 + j];
#pragma unroll
    for (int i = 0; i < 8; i++) num += q[i] * s[i * 8 + j];
    float o = num * rden * tmp * xsca[b * 64 + h * 8 + j] * bf2f(gp[(long)j * NP]);
    op[(long)j * NP] = f2bf(o);
  }
}

// ---------------- proj GEMM + residual + sigma2 + xb2 emit
__global__ __launch_bounds__(256) void k_proj(const u16* __restrict__ O,
                                              const float* __restrict__ WpT,
                                              float* __restrict__ xo,
                                              u16* __restrict__ xb2) {
  int n = blockIdx.x * 256 + threadIdx.x;
  int b = blockIdx.z;
  const u16* ip = O + (long)b * 64 * NP + n;
  float acc[64];
#pragma unroll
  for (int j = 0; j < 64; j++) acc[j] = 0.f;
#pragma unroll 2
  for (int ci = 0; ci < 64; ci++) {
    float xv = bf2f(ip[(long)ci * NP]);
    const float* wr = WpT + ci * 64;
#pragma unroll
    for (int j = 0; j < 64; j++) acc[j] += wr[j] * xv;
  }
  float* xp = xo + (long)b * 64 * NP + n;
  float s1 = 0.f, s2 = 0.f;
#pragma unroll
  for (int c = 0; c < 64; c++) {
    float v = xp[(long)c * NP] + acc[c];
    acc[c] = v;
    s1 += v; s2 += v * v;
  }
#pragma unroll
  for (int c = 0; c < 64; c++) xp[(long)c * NP] = acc[c];
  float m = s1 * (1.f / 64.f);
  float var = s2 * (1.f / 64.f) - m * m;
  float sg = rsqrtf(var + 1e-5f);
  u16* bp = xb2 + (long)b * 64 * NP + n;
#pragma unroll
  for (int c = 0; c < 64; c++) bp[(long)c * NP] = f2bf(acc[c] * sg);
}

// ---------------- pout GEMM (170->64) + residual
__global__ __launch_bounds__(256) void k_pout(const u16* __restrict__ Hb,
                                              const float* __restrict__ WoT,
                                              float* __restrict__ xo) {
  int n = blockIdx.x * 256 + threadIdx.x;
  int b = blockIdx.z;
  const u16* ip = Hb + (long)b * 170 * NP + n;
  float acc[64];
#pragma unroll
  for (int j = 0; j < 64; j++) acc[j] = 0.f;
#pragma unroll 2
  for (int ci = 0; ci < 170; ci++) {
    float xv = bf2f(ip[(long)ci * NP]);
    const float* wr = WoT + ci * 64;
#pragma unroll
    for (int j = 0; j < 64; j++) acc[j] += wr[j] * xv;
  }
  float* xp = xo + (long)b * 64 * NP + n;
#pragma unroll
  for (int c = 0; c < 64; c++) xp[(long)c * NP] += acc[c];
}

// ================================================================ launcher
extern "C" void kernel_launch(void* const* d_in, const int* in_sizes, int n_in,
                              void* d_out, int out_size, void* d_ws, size_t ws_size,
                              hipStream_t stream) {
  const float* x        = (const float*)d_in[0];
  const float* ln1_w    = (const float*)d_in[1];
  const float* sca_w    = (const float*)d_in[2];
  const float* sca_b    = (const float*)d_in[3];
  const float* dw1_w    = (const float*)d_in[4];
  const float* dw2_w    = (const float*)d_in[5];
  const float* qkv_w    = (const float*)d_in[6];
  const float* qkv_dw_w = (const float*)d_in[7];
  const float* temp     = (const float*)d_in[8];
  const float* r3w = (const float*)d_in[9],  *r3b = (const float*)d_in[10];
  const float* r5w = (const float*)d_in[11], *r5b = (const float*)d_in[12];
  const float* r7w = (const float*)d_in[13], *r7b = (const float*)d_in[14];
  const float* proj_w   = (const float*)d_in[15];
  const float* ln2_w    = (const float*)d_in[16];
  const float* pin_w    = (const float*)d_in[17];
  const float* ffn_dw_w = (const float*)d_in[18];
  const float* pout_w   = (const float*)d_in[19];
  float* out = (float*)d_out;

  const long US = 16777216;                 // ushorts per 64ch bf16 tensor (B*64*NP)
  u16* xb1 = (u16*)d_ws;
  u16* Qn  = xb1 + US;
  u16* Kn  = Qn + US;
  u16* G   = Kn + US;
  u16* O   = G + US;
  u16* Pb  = O + US;                        // 384*NP ushorts per-batch scratch
  float* refW    = (float*)(Pb + (long)384 * NP);
  float* stats   = refW + 2097152;          // 2560
  float* meanraw = stats + 2560;            // 256
  float* xscab   = meanraw + 256;           // 256
  float* W1T     = xscab + 256;             // 64*320
  float* W2T     = W1T + 20480;             // 64*384
  float* WpT     = W2T + 24576;             // 64*64
  float* WoT     = WpT + 4096;              // 170*64
  u16* Hb  = Qn;                            // FFN gated 170ch bf16, reuses Qn..G
  u16* xb2 = xb1;                           // reuses xb1

  const size_t needed = (size_t)((char*)(WoT + 10880) - (char*)d_ws);
  if (ws_size < needed) {
    fprintf(stderr, "kernel_launch: ws_size %zu < needed %zu\n", ws_size, needed);
    return;
  }

  hipMemsetAsync(stats, 0, (2560 + 256) * 4, stream);  // stats + meanraw

  k_foldW1<<<80, 256, 0, stream>>>(qkv_w, dw1_w, ln1_w, W1T);
  k_foldW2<<<96, 256, 0, stream>>>(pin_w, ln2_w, W2T);
  k_tproj<<<16, 256, 0, stream>>>(proj_w, WpT);
  k_tpout<<<43, 256, 0, stream>>>(pout_w, WoT);

  k_trans_stats<<<dim3(1024, BB), 256, 0, stream>>>(x, out, xb1, meanraw);
  k_xsca<<<1, 256, 0, stream>>>(meanraw, ln1_w, sca_w, sca_b, xscab);

  for (int b = 0; b < BB; b++) {
    const u16* xb1b = xb1 + (long)b * 64 * NP;
    u16* Qnb = Qn + (long)b * 64 * NP;
    u16* Knb = Kn + (long)b * 64 * NP;
    u16* Gb  = G + (long)b * 64 * NP;
    k_gemm64<<<dim3(256, 5), 256, 0, stream>>>(xb1b, W1T, 320, Pb);
    k_dwn<<<dim3(256, 8), 256, 0, stream>>>(Pb, qkv_dw_w, Qnb);
    k_dwn<<<dim3(256, 8), 256, 0, stream>>>(Pb + (long)64 * NP, qkv_dw_w + 64 * 9, Knb);
    k_dwv<<<dim3(256, 8), 256, 0, stream>>>(Pb + (long)128 * NP, qkv_dw_w + 128 * 9,
                                            Knb, stats + b * 640);
    k_dwg<<<dim3(256, 64), 256, 0, stream>>>(Pb + (long)192 * NP, dw2_w, Gb);
  }

  k_refine<<<dim3(8, 8, 32), 256, 0, stream>>>(Qn, Kn, r3w, r3b, r5w, r5b, r7w, r7b, refW);
  k_attn_out<<<dim3(256, 32), 256, 0, stream>>>(Qn, stats, refW, temp, xscab, G, O);
  k_proj<<<dim3(256, 1, BB), 256, 0, stream>>>(O, WpT, out, xb2);

  for (int b = 0; b < BB; b++) {
    const u16* xb2b = xb2 + (long)b * 64 * NP;
    u16* Hbb = Hb + (long)b * 170 * NP;
    k_gemm64<<<dim3(256, 6), 256, 0, stream>>>(xb2b, W2T, 384, Pb);
    k_dwgate<<<dim3(256, 170), 256, 0, stream>>>(Pb, ffn_dw_w, Hbb);
  }
  k_pout<<<dim3(256, 1, BB), 256, 0, stream>>>(Hb, WoT, out);
}